// Round 6
// baseline (236.610 us; speedup 1.0000x reference)
//
#include <hip/hip_runtime.h>
#include <hip/hip_bf16.h>
#include <cstdint>
#include <cstddef>

typedef __attribute__((ext_vector_type(8))) short bf16x8;
typedef __attribute__((ext_vector_type(4))) float floatx4;
typedef __attribute__((ext_vector_type(16))) float floatx16;
typedef __attribute__((ext_vector_type(2))) unsigned uintx2;

#define SCALE_L2E 0.20823560929138437f  /* (1/sqrt(48)) * log2(e) */

#define BPH 128          // B*P*H = 8*4*4
#define SEQ 1024
#define DMODEL 192
#define DHEAD 48
#define MROWS 32768      // B*P*N
#define RESCALE_THR 11.5f  /* log2 domain ~ e^8 */

#define ZERO16 {0.f,0.f,0.f,0.f,0.f,0.f,0.f,0.f,0.f,0.f,0.f,0.f,0.f,0.f,0.f,0.f}

__device__ __forceinline__ unsigned short bfu(float f) {
    return __bfloat16_as_ushort(__float2bfloat16(f));
}
__device__ __forceinline__ unsigned pk2(float lo, float hi) {
    return (unsigned)bfu(lo) | ((unsigned)bfu(hi) << 16);
}

// ---------------------------------------------------------------------------
// Kernel 1: QKV projection (unchanged from R5 — proven).
// ---------------------------------------------------------------------------
__global__ __launch_bounds__(256) void qkv_kernel(
    const float* __restrict__ x,
    const float* __restrict__ w_qkv,
    const float* __restrict__ b_qkv,
    unsigned short* __restrict__ q_ws,
    unsigned short* __restrict__ k_ws,
    unsigned short* __restrict__ vt_ws)
{
    __shared__ unsigned short a_lds[64 * 200];
    __shared__ unsigned short w_lds[64 * 200];
    const int t = threadIdx.x;
    const int m0 = blockIdx.x * 64;
    const int n0 = blockIdx.y * 64;

    #pragma unroll
    for (int i = 0; i < 12; ++i) {
        int idx = t + i * 256;
        int row = idx / 48, c4 = idx % 48;
        float4 v = *reinterpret_cast<const float4*>(x + (size_t)(m0 + row) * DMODEL + c4 * 4);
        uintx2 p; p.x = pk2(v.x, v.y); p.y = pk2(v.z, v.w);
        *reinterpret_cast<uintx2*>(&a_lds[row * 200 + c4 * 4]) = p;
    }
    #pragma unroll
    for (int i = 0; i < 12; ++i) {
        int idx = t + i * 256;
        int row = idx / 48, c4 = idx % 48;
        float4 v = *reinterpret_cast<const float4*>(w_qkv + (size_t)(n0 + row) * DMODEL + c4 * 4);
        uintx2 p; p.x = pk2(v.x, v.y); p.y = pk2(v.z, v.w);
        *reinterpret_cast<uintx2*>(&w_lds[row * 200 + c4 * 4]) = p;
    }
    __syncthreads();

    const int lane = t & 63, w = t >> 6;
    const int lrow = lane & 15, lhi = lane >> 4;

    floatx4 zf = {0.f, 0.f, 0.f, 0.f};
    floatx4 acc[4] = {zf, zf, zf, zf};

    #pragma unroll
    for (int ks = 0; ks < 6; ++ks) {
        bf16x8 af = *reinterpret_cast<const bf16x8*>(&a_lds[(w * 16 + lrow) * 200 + ks * 32 + lhi * 8]);
        #pragma unroll
        for (int cb = 0; cb < 4; ++cb) {
            bf16x8 bfr = *reinterpret_cast<const bf16x8*>(&w_lds[(cb * 16 + lrow) * 200 + ks * 32 + lhi * 8]);
            acc[cb] = __builtin_amdgcn_mfma_f32_16x16x32_bf16(af, bfr, acc[cb], 0, 0, 0);
        }
    }

    const int sec = n0 / 192;  // 0=q, 1=k, 2=v (uniform per block)
    if (sec == 2) {
        __syncthreads();  // a_lds reads done; reuse as [64 c][72 pad] tile
        #pragma unroll
        for (int cb = 0; cb < 4; ++cb) {
            float bias = b_qkv[n0 + cb * 16 + lrow];
            #pragma unroll
            for (int r = 0; r < 4; ++r)
                a_lds[(cb * 16 + lrow) * 72 + (w * 16 + lhi * 4 + r)] = bfu(acc[cb][r] + bias);
        }
        __syncthreads();
        const int bp = m0 >> 10, nb = m0 & 1023;
        #pragma unroll
        for (int i = 0; i < 2; ++i) {
            int ch = t + i * 256;
            int c_local = ch >> 3, seg = ch & 7;
            int cc = n0 + c_local - 384;
            int h = cc / 48, dd = cc - h * 48;
            *reinterpret_cast<bf16x8*>(
                &vt_ws[((size_t)(bp * 4 + h) * DHEAD + dd) * SEQ + nb + seg * 8]) =
                *reinterpret_cast<const bf16x8*>(&a_lds[c_local * 72 + seg * 8]);
        }
    } else {
        #pragma unroll
        for (int cb = 0; cb < 4; ++cb) {
            int c = n0 + cb * 16 + lrow;
            int cc = c - sec * 192;
            int h = cc / 48, dd = cc - h * 48;
            float bias = b_qkv[c];
            #pragma unroll
            for (int r = 0; r < 4; ++r) {
                int m = m0 + w * 16 + lhi * 4 + r;
                float val = acc[cb][r] + bias;
                int bp = m >> 10, n = m & 1023;
                int bph = bp * 4 + h;
                if (sec == 0) {
                    q_ws[((size_t)bph * SEQ + n) * DHEAD + dd] = bfu(val * SCALE_L2E);
                } else {
                    k_ws[((size_t)bph * SEQ + n) * DHEAD + dd] = bfu(val);
                }
            }
        }
    }
}

// ---------------------------------------------------------------------------
// Kernel 2: flash attention. Block = 4 waves, same bph — K/V tiles now staged
// ONCE per block in double-buffered LDS (12KB/tile): each thread stages 3x16B
// chunks (T14 split: global loads issued at tile top, ds_write after compute,
// one barrier/tile). Chunk layout [kshi][row]*16B -> stride-16 ds_read/write,
// zero bank conflicts. Compute body verbatim R5 (correctness-proven), with
// fragments sourced from LDS. XCD-swizzled dispatch unchanged.
// ---------------------------------------------------------------------------
__global__ __launch_bounds__(256, 4) void attn_kernel(
    const unsigned short* __restrict__ q_ws,
    const unsigned short* __restrict__ k_ws,
    const unsigned short* __restrict__ vt_ws,
    unsigned short* __restrict__ z_ws)
{
    __shared__ unsigned short k_lds[2][384 * 8];   // 6 KB per buffer
    __shared__ unsigned short v_lds[2][384 * 8];   // 6 KB per buffer

    const int t = threadIdx.x, lane = t & 63, w = t >> 6;
    const int q31 = lane & 31, hi = lane >> 5;
    const int d = blockIdx.x;
    const int bph = (d & 7) | ((d >> 6) << 3);
    const int qc = (d >> 3) & 7;
    const int q0 = qc * 128 + w * 32;
    const int bp = bph >> 2, h = bph & 3;

    // ---- per-thread staging descriptors (3 chunks of 16B per tile) ----
    // K chunks c in [0,384): kshi=c>>6 (ks=kshi>>1, khi=kshi&1), row=c&63
    //   holds k_ws[bph][kt0+row][ks*16+khi*8 .. +8); LDS ushort off = c*8
    // V chunks c in [0,384): vkhi=c/48 (ksv=vkhi>>1, vhi=vkhi&1), dd=c%48
    //   holds vt_ws[bph][dd][kt0+ksv*16+vhi*8 .. +8); LDS ushort off = c*8
    const size_t kbase = (size_t)bph * SEQ;
    const size_t vbase = (size_t)bph * DHEAD;

    // chunk 0: cc = t (always K)
    const int kshi0 = t >> 6, row0 = t & 63;
    const unsigned short* s0p = k_ws + (kbase + row0) * 48 + (kshi0 >> 1) * 16 + (kshi0 & 1) * 8;
    unsigned short* d0A = &k_lds[0][t * 8];
    unsigned short* d0B = &k_lds[1][t * 8];

    // chunk 1: cc = t+256 (K for t<128, else V chunk t-128)
    const unsigned short* s1p;
    unsigned short *d1A, *d1B;
    size_t step1;
    if (t < 128) {
        int c = t + 256, kshi = c >> 6, row = c & 63;
        s1p = k_ws + (kbase + row) * 48 + (kshi >> 1) * 16 + (kshi & 1) * 8;
        step1 = 64 * 48;
        d1A = &k_lds[0][c * 8]; d1B = &k_lds[1][c * 8];
    } else {
        int c = t - 128, vkhi = c / 48, dd = c - vkhi * 48;
        s1p = vt_ws + (vbase + dd) * SEQ + (vkhi >> 1) * 16 + (vkhi & 1) * 8;
        step1 = 64;
        d1A = &v_lds[0][c * 8]; d1B = &v_lds[1][c * 8];
    }

    // chunk 2: V chunk c2 = t+128 (in [128,384))
    const int c2 = t + 128, vkhi2 = c2 / 48, dd2 = c2 - vkhi2 * 48;
    const unsigned short* s2p = vt_ws + (vbase + dd2) * SEQ + (vkhi2 >> 1) * 16 + (vkhi2 & 1) * 8;
    unsigned short* d2A = &v_lds[0][c2 * 8];
    unsigned short* d2B = &v_lds[1][c2 * 8];

    // ---- Q fragments (3 k-slices of 16), pre-scaled by SCALE*log2e ----
    bf16x8 qf[3];
    {
        const unsigned short* qp = q_ws + (kbase + q0 + q31) * DHEAD + hi * 8;
        #pragma unroll
        for (int ks = 0; ks < 3; ++ks)
            qf[ks] = *reinterpret_cast<const bf16x8*>(qp + ks * 16);
    }

    const int vrow1m = (32 + q31 > 47) ? 47 : (32 + q31);  // dup row 47, outputs discarded

    floatx16 oa0 = ZERO16, oa1 = ZERO16;
    float m_prev = -INFINITY, l_sum = 0.f;

    // ---- prologue: stage tile 0 into buffer A ----
    {
        bf16x8 a = *reinterpret_cast<const bf16x8*>(s0p);
        bf16x8 b = *reinterpret_cast<const bf16x8*>(s1p);
        bf16x8 c = *reinterpret_cast<const bf16x8*>(s2p);
        *reinterpret_cast<bf16x8*>(d0A) = a;
        *reinterpret_cast<bf16x8*>(d1A) = b;
        *reinterpret_cast<bf16x8*>(d2A) = c;
    }
    __syncthreads();

    #pragma unroll 2
    for (int kt = 0; kt < 16; ++kt) {
        const int nt = (kt + 1) & 15;   // wrap: final iter re-stages tile 0 (unused)
        const unsigned short* kb = k_lds[kt & 1];
        const unsigned short* vb = v_lds[kt & 1];

        // ---- 1. issue prefetch loads for tile nt (latency hidden by compute) ----
        bf16x8 pg0 = *reinterpret_cast<const bf16x8*>(s0p + (size_t)nt * (64 * 48));
        bf16x8 pg1 = *reinterpret_cast<const bf16x8*>(s1p + (size_t)nt * step1);
        bf16x8 pg2 = *reinterpret_cast<const bf16x8*>(s2p + (size_t)nt * 64);

        // ---- 2. fragments from LDS (stride-16, conflict-free) ----
        bf16x8 kf[6], vf0[4], vf1[4];
        #pragma unroll
        for (int ks = 0; ks < 3; ++ks) {
            kf[ks]     = *reinterpret_cast<const bf16x8*>(&kb[((ks * 2 + hi) * 64 + q31) * 8]);
            kf[ks + 3] = *reinterpret_cast<const bf16x8*>(&kb[((ks * 2 + hi) * 64 + q31 + 32) * 8]);
        }
        #pragma unroll
        for (int ksv = 0; ksv < 4; ++ksv) {
            vf0[ksv] = *reinterpret_cast<const bf16x8*>(&vb[((ksv * 2 + hi) * 48 + q31) * 8]);
            vf1[ksv] = *reinterpret_cast<const bf16x8*>(&vb[((ksv * 2 + hi) * 48 + vrow1m) * 8]);
        }

        // ---- S^T = K . Q^T ----
        floatx16 s0 = ZERO16, s1 = ZERO16;
        __builtin_amdgcn_s_setprio(1);
        #pragma unroll
        for (int ks = 0; ks < 3; ++ks) {
            s0 = __builtin_amdgcn_mfma_f32_32x32x16_bf16(kf[ks],     qf[ks], s0, 0, 0, 0);
            s1 = __builtin_amdgcn_mfma_f32_32x32x16_bf16(kf[ks + 3], qf[ks], s1, 0, 0, 0);
        }
        __builtin_amdgcn_s_setprio(0);

        // ---- tree max (depth 5) + cross-half shfl ----
        float a[8];
        #pragma unroll
        for (int u = 0; u < 8; ++u)
            a[u] = fmaxf(fmaxf(s0[2*u], s0[2*u+1]), fmaxf(s1[2*u], s1[2*u+1]));
        float m01 = fmaxf(fmaxf(a[0], a[1]), fmaxf(a[2], a[3]));
        float m23 = fmaxf(fmaxf(a[4], a[5]), fmaxf(a[6], a[7]));
        float tmax = fmaxf(m01, m23);
        tmax = fmaxf(tmax, __shfl_xor(tmax, 32, 64));

        if (!__all((int)(tmax <= m_prev + RESCALE_THR))) {
            const float mnew = fmaxf(m_prev, tmax);
            const float scale = exp2f(m_prev - mnew);
            m_prev = mnew;
            l_sum *= scale;
            oa0 = oa0 * scale;
            oa1 = oa1 * scale;
        }
        const float mref = m_prev;

        // ---- exp + pack (split accumulators) ----
        unsigned W0[8], W1[8];
        float tsA = 0.f, tsB = 0.f;
        #pragma unroll
        for (int u = 0; u < 8; ++u) {
            float e0 = __builtin_amdgcn_exp2f(s0[2*u]   - mref);
            float e1 = __builtin_amdgcn_exp2f(s0[2*u+1] - mref);
            tsA += e0 + e1;
            W0[u] = pk2(e0, e1);
        }
        #pragma unroll
        for (int u = 0; u < 8; ++u) {
            float e0 = __builtin_amdgcn_exp2f(s1[2*u]   - mref);
            float e1 = __builtin_amdgcn_exp2f(s1[2*u+1] - mref);
            tsB += e0 + e1;
            W1[u] = pk2(e0, e1);
        }
        float ts = tsA + tsB;
        ts += __shfl_xor(ts, 32, 64);
        l_sum += ts;

        // ---- cross-half P redistribution (proven shfl_xor + select form) ----
        unsigned X0[8], X1[8];
        #pragma unroll
        for (int u = 0; u < 8; ++u) X0[u] = __shfl_xor(W0[u], 32, 64);
        #pragma unroll
        for (int u = 0; u < 8; ++u) X1[u] = __shfl_xor(W1[u], 32, 64);

        // ---- O^T += Vt . P^T ----
        union U { bf16x8 v; unsigned wd[4]; };
        __builtin_amdgcn_s_setprio(1);
        {
            U pa;
            pa.wd[0] = hi ? X0[2] : W0[0];
            pa.wd[1] = hi ? X0[3] : W0[1];
            pa.wd[2] = hi ? W0[2] : X0[0];
            pa.wd[3] = hi ? W0[3] : X0[1];
            oa0 = __builtin_amdgcn_mfma_f32_32x32x16_bf16(vf0[0], pa.v, oa0, 0, 0, 0);
            oa1 = __builtin_amdgcn_mfma_f32_32x32x16_bf16(vf1[0], pa.v, oa1, 0, 0, 0);
        }
        {
            U pb;
            pb.wd[0] = hi ? X0[6] : W0[4];
            pb.wd[1] = hi ? X0[7] : W0[5];
            pb.wd[2] = hi ? W0[6] : X0[4];
            pb.wd[3] = hi ? W0[7] : X0[5];
            oa0 = __builtin_amdgcn_mfma_f32_32x32x16_bf16(vf0[1], pb.v, oa0, 0, 0, 0);
            oa1 = __builtin_amdgcn_mfma_f32_32x32x16_bf16(vf1[1], pb.v, oa1, 0, 0, 0);
        }
        {
            U pc;
            pc.wd[0] = hi ? X1[2] : W1[0];
            pc.wd[1] = hi ? X1[3] : W1[1];
            pc.wd[2] = hi ? W1[2] : X1[0];
            pc.wd[3] = hi ? W1[3] : X1[1];
            oa0 = __builtin_amdgcn_mfma_f32_32x32x16_bf16(vf0[2], pc.v, oa0, 0, 0, 0);
            oa1 = __builtin_amdgcn_mfma_f32_32x32x16_bf16(vf1[2], pc.v, oa1, 0, 0, 0);
        }
        {
            U pd;
            pd.wd[0] = hi ? X1[6] : W1[4];
            pd.wd[1] = hi ? X1[7] : W1[5];
            pd.wd[2] = hi ? W1[6] : X1[4];
            pd.wd[3] = hi ? W1[7] : X1[5];
            oa0 = __builtin_amdgcn_mfma_f32_32x32x16_bf16(vf0[3], pd.v, oa0, 0, 0, 0);
            oa1 = __builtin_amdgcn_mfma_f32_32x32x16_bf16(vf1[3], pd.v, oa1, 0, 0, 0);
        }
        __builtin_amdgcn_s_setprio(0);

        // ---- 3. write prefetched tile nt into the other buffer ----
        {
            unsigned short* wd0 = (kt & 1) ? d0A : d0B;
            unsigned short* wd1 = (kt & 1) ? d1A : d1B;
            unsigned short* wd2 = (kt & 1) ? d2A : d2B;
            *reinterpret_cast<bf16x8*>(wd0) = pg0;
            *reinterpret_cast<bf16x8*>(wd1) = pg1;
            *reinterpret_cast<bf16x8*>(wd2) = pg2;
        }
        __syncthreads();
    }

    // ---- normalize + write z [bp][n][192] bf16 (paired u32 stores) ----
    const float inv = 1.0f / l_sum;
    unsigned* zp = reinterpret_cast<unsigned*>(
        z_ws + ((size_t)bp * SEQ + q0 + q31) * DMODEL + h * DHEAD);
    #pragma unroll
    for (int u = 0; u < 8; ++u) {
        int dd = 2 * (u & 1) + 8 * (u >> 1) + 4 * hi;       // d, d+1
        zp[dd >> 1] = pk2(oa0[2*u] * inv, oa0[2*u+1] * inv);
    }
    #pragma unroll
    for (int u = 0; u < 4; ++u) {
        int dd = 32 + 2 * (u & 1) + 8 * (u >> 1) + 4 * hi;  // 32..47 only
        zp[dd >> 1] = pk2(oa1[2*u] * inv, oa1[2*u+1] * inv);
    }
}

// ---------------------------------------------------------------------------
// Kernel 3: output projection (unchanged from R5 — proven).
// ---------------------------------------------------------------------------
__global__ __launch_bounds__(256) void proj_kernel(
    const unsigned short* __restrict__ z_ws,
    const float* __restrict__ w_proj,
    const float* __restrict__ b_proj,
    float* __restrict__ out)
{
    __shared__ unsigned short a_lds[64 * 200];
    __shared__ unsigned short w_lds[64 * 200];
    const int t = threadIdx.x;
    const int m0 = blockIdx.x * 64;
    const int n0 = blockIdx.y * 64;

    for (int i = t; i < 1536; i += 256) {
        int row = i / 24, c8 = i % 24;
        *reinterpret_cast<bf16x8*>(&a_lds[row * 200 + c8 * 8]) =
            *reinterpret_cast<const bf16x8*>(&z_ws[(size_t)(m0 + row) * DMODEL + c8 * 8]);
    }
    #pragma unroll
    for (int i = 0; i < 12; ++i) {
        int idx = t + i * 256;
        int row = idx / 48, c4 = idx % 48;
        float4 v = *reinterpret_cast<const float4*>(w_proj + (size_t)(n0 + row) * DMODEL + c4 * 4);
        uintx2 p; p.x = pk2(v.x, v.y); p.y = pk2(v.z, v.w);
        *reinterpret_cast<uintx2*>(&w_lds[row * 200 + c4 * 4]) = p;
    }
    __syncthreads();

    const int lane = t & 63, w = t >> 6;
    const int lrow = lane & 15, lhi = lane >> 4;

    floatx4 zf = {0.f, 0.f, 0.f, 0.f};
    floatx4 acc[4] = {zf, zf, zf, zf};

    #pragma unroll
    for (int ks = 0; ks < 6; ++ks) {
        bf16x8 af = *reinterpret_cast<const bf16x8*>(&a_lds[(w * 16 + lrow) * 200 + ks * 32 + lhi * 8]);
        #pragma unroll
        for (int cb = 0; cb < 4; ++cb) {
            bf16x8 bfr = *reinterpret_cast<const bf16x8*>(&w_lds[(cb * 16 + lrow) * 200 + ks * 32 + lhi * 8]);
            acc[cb] = __builtin_amdgcn_mfma_f32_16x16x32_bf16(af, bfr, acc[cb], 0, 0, 0);
        }
    }

    #pragma unroll
    for (int cb = 0; cb < 4; ++cb) {
        int c = n0 + cb * 16 + lrow;
        float bias = b_proj[c];
        #pragma unroll
        for (int r = 0; r < 4; ++r) {
            int m = m0 + w * 16 + lhi * 4 + r;
            out[(size_t)m * DMODEL + c] = acc[cb][r] + bias;
        }
    }
}

// ---------------------------------------------------------------------------
extern "C" void kernel_launch(void* const* d_in, const int* in_sizes, int n_in,
                              void* d_out, int out_size, void* d_ws, size_t ws_size,
                              hipStream_t stream) {
    const float* x      = (const float*)d_in[0];
    const float* w_qkv  = (const float*)d_in[1];
    const float* b_qkv  = (const float*)d_in[2];
    const float* w_proj = (const float*)d_in[3];
    const float* b_proj = (const float*)d_in[4];
    float* out = (float*)d_out;

    unsigned short* q_ws  = (unsigned short*)d_ws;
    unsigned short* k_ws  = q_ws  + (size_t)BPH * SEQ * DHEAD;   // 6.29M elems each
    unsigned short* vt_ws = k_ws  + (size_t)BPH * SEQ * DHEAD;
    unsigned short* z_ws  = vt_ws + (size_t)BPH * DHEAD * SEQ;
    // total ws usage: 4 * 12.58 MB = 50.3 MB

    qkv_kernel<<<dim3(512, 9), 256, 0, stream>>>(x, w_qkv, b_qkv, q_ws, k_ws, vt_ws);
    attn_kernel<<<1024, 256, 0, stream>>>(q_ws, k_ws, vt_ws, z_ws);
    proj_kernel<<<dim3(512, 3), 256, 0, stream>>>(z_ws, w_proj, b_proj, out);
}

// Round 7
// 119.121 us; speedup vs baseline: 1.9863x; 1.9863x over previous
//
#include <hip/hip_runtime.h>
#include <hip/hip_bf16.h>
#include <cstdint>
#include <cstddef>

typedef __attribute__((ext_vector_type(8))) short bf16x8;
typedef __attribute__((ext_vector_type(4))) float floatx4;
typedef __attribute__((ext_vector_type(16))) float floatx16;
typedef __attribute__((ext_vector_type(2))) unsigned uintx2;

#define SCALE_L2E 0.20823560929138437f  /* (1/sqrt(48)) * log2(e) */

#define BPH 128          // B*P*H = 8*4*4
#define SEQ 1024
#define DMODEL 192
#define DHEAD 48
#define MROWS 32768      // B*P*N
#define RESCALE_THR 11.5f  /* log2 domain ~ e^8 */

#define ZERO16 {0.f,0.f,0.f,0.f,0.f,0.f,0.f,0.f,0.f,0.f,0.f,0.f,0.f,0.f,0.f,0.f}

__device__ __forceinline__ unsigned short bfu(float f) {
    return __bfloat16_as_ushort(__float2bfloat16(f));
}
__device__ __forceinline__ unsigned pk2(float lo, float hi) {
    return (unsigned)bfu(lo) | ((unsigned)bfu(hi) << 16);
}
// async 16B global -> LDS (no VGPR round-trip); vmcnt-counted, drained by the
// compiler's waitcnt before s_barrier.
__device__ __forceinline__ void gload16(const unsigned short* g, unsigned short* l) {
    __builtin_amdgcn_global_load_lds(
        (const __attribute__((address_space(1))) unsigned int*)g,
        (__attribute__((address_space(3))) unsigned int*)l,
        16, 0, 0);
}

// ---------------------------------------------------------------------------
// Kernel 1: QKV projection (unchanged — proven).
// ---------------------------------------------------------------------------
__global__ __launch_bounds__(256) void qkv_kernel(
    const float* __restrict__ x,
    const float* __restrict__ w_qkv,
    const float* __restrict__ b_qkv,
    unsigned short* __restrict__ q_ws,
    unsigned short* __restrict__ k_ws,
    unsigned short* __restrict__ vt_ws)
{
    __shared__ unsigned short a_lds[64 * 200];
    __shared__ unsigned short w_lds[64 * 200];
    const int t = threadIdx.x;
    const int m0 = blockIdx.x * 64;
    const int n0 = blockIdx.y * 64;

    #pragma unroll
    for (int i = 0; i < 12; ++i) {
        int idx = t + i * 256;
        int row = idx / 48, c4 = idx % 48;
        float4 v = *reinterpret_cast<const float4*>(x + (size_t)(m0 + row) * DMODEL + c4 * 4);
        uintx2 p; p.x = pk2(v.x, v.y); p.y = pk2(v.z, v.w);
        *reinterpret_cast<uintx2*>(&a_lds[row * 200 + c4 * 4]) = p;
    }
    #pragma unroll
    for (int i = 0; i < 12; ++i) {
        int idx = t + i * 256;
        int row = idx / 48, c4 = idx % 48;
        float4 v = *reinterpret_cast<const float4*>(w_qkv + (size_t)(n0 + row) * DMODEL + c4 * 4);
        uintx2 p; p.x = pk2(v.x, v.y); p.y = pk2(v.z, v.w);
        *reinterpret_cast<uintx2*>(&w_lds[row * 200 + c4 * 4]) = p;
    }
    __syncthreads();

    const int lane = t & 63, w = t >> 6;
    const int lrow = lane & 15, lhi = lane >> 4;

    floatx4 zf = {0.f, 0.f, 0.f, 0.f};
    floatx4 acc[4] = {zf, zf, zf, zf};

    #pragma unroll
    for (int ks = 0; ks < 6; ++ks) {
        bf16x8 af = *reinterpret_cast<const bf16x8*>(&a_lds[(w * 16 + lrow) * 200 + ks * 32 + lhi * 8]);
        #pragma unroll
        for (int cb = 0; cb < 4; ++cb) {
            bf16x8 bfr = *reinterpret_cast<const bf16x8*>(&w_lds[(cb * 16 + lrow) * 200 + ks * 32 + lhi * 8]);
            acc[cb] = __builtin_amdgcn_mfma_f32_16x16x32_bf16(af, bfr, acc[cb], 0, 0, 0);
        }
    }

    const int sec = n0 / 192;  // 0=q, 1=k, 2=v (uniform per block)
    if (sec == 2) {
        __syncthreads();  // a_lds reads done; reuse as [64 c][72 pad] tile
        #pragma unroll
        for (int cb = 0; cb < 4; ++cb) {
            float bias = b_qkv[n0 + cb * 16 + lrow];
            #pragma unroll
            for (int r = 0; r < 4; ++r)
                a_lds[(cb * 16 + lrow) * 72 + (w * 16 + lhi * 4 + r)] = bfu(acc[cb][r] + bias);
        }
        __syncthreads();
        const int bp = m0 >> 10, nb = m0 & 1023;
        #pragma unroll
        for (int i = 0; i < 2; ++i) {
            int ch = t + i * 256;
            int c_local = ch >> 3, seg = ch & 7;
            int cc = n0 + c_local - 384;
            int h = cc / 48, dd = cc - h * 48;
            *reinterpret_cast<bf16x8*>(
                &vt_ws[((size_t)(bp * 4 + h) * DHEAD + dd) * SEQ + nb + seg * 8]) =
                *reinterpret_cast<const bf16x8*>(&a_lds[c_local * 72 + seg * 8]);
        }
    } else {
        #pragma unroll
        for (int cb = 0; cb < 4; ++cb) {
            int c = n0 + cb * 16 + lrow;
            int cc = c - sec * 192;
            int h = cc / 48, dd = cc - h * 48;
            float bias = b_qkv[c];
            #pragma unroll
            for (int r = 0; r < 4; ++r) {
                int m = m0 + w * 16 + lhi * 4 + r;
                float val = acc[cb][r] + bias;
                int bp = m >> 10, n = m & 1023;
                int bph = bp * 4 + h;
                if (sec == 0) {
                    q_ws[((size_t)bph * SEQ + n) * DHEAD + dd] = bfu(val * SCALE_L2E);
                } else {
                    k_ws[((size_t)bph * SEQ + n) * DHEAD + dd] = bfu(val);
                }
            }
        }
    }
}

// ---------------------------------------------------------------------------
// Kernel 2: flash attention. Block = 4 waves, same bph. K/V tiles staged once
// per block via async global_load_lds (zero staging VGPRs), double-buffered
// 2-phase: issue tile t+1's loads, compute tile t from LDS, one barrier/tile.
// Chunk layout [kshi][row]*16B -> stride-16 ds ops, conflict-free (mapping
// correctness-proven in R6). Compute body = R3's proven per-kvb form (~102
// VGPR peak, under the launch_bounds(256,4) cap of 128 -> no spill).
// ---------------------------------------------------------------------------
__global__ __launch_bounds__(256, 4) void attn_kernel(
    const unsigned short* __restrict__ q_ws,
    const unsigned short* __restrict__ k_ws,
    const unsigned short* __restrict__ vt_ws,
    unsigned short* __restrict__ z_ws)
{
    __shared__ unsigned short k_lds[2][384 * 8];   // 6 KB per buffer
    __shared__ unsigned short v_lds[2][384 * 8];   // 6 KB per buffer

    const int t = threadIdx.x, lane = t & 63, w = t >> 6;
    const int q31 = lane & 31, hi = lane >> 5;
    const int d = blockIdx.x;
    const int bph = (d & 7) | ((d >> 6) << 3);
    const int qc = (d >> 3) & 7;
    const int q0 = qc * 128 + w * 32;
    const int bp = bph >> 2, h = bph & 3;

    const size_t kbase = (size_t)bph * SEQ;
    const size_t vbase = (size_t)bph * DHEAD;

    // ---- per-thread staging chunks (3 x 16B per tile, wave-uniform LDS base) ----
    // K chunk c in [0,384): kshi=c>>6, row=c&63; src k_ws[bph][kt0+row][kshi*8]
    // V chunk c in [0,384): vkhi=c/48, dd=c%48;  src vt_ws[bph][dd][kt0+vkhi*8]
    // chunk0: K chunk t          (all waves K)
    const unsigned short* s0p = k_ws + (kbase + (t & 63)) * 48 + (t >> 6) * 8;
    // chunk1: waves 0-1 -> K chunk t+256 ; waves 2-3 -> V chunk t-128
    const unsigned short* s1p;
    size_t step1;   // src elements per kv-step of 1 (times kt0)
    int c1;
    const bool c1k = (t < 128);
    if (c1k) {
        c1 = t + 256;
        s1p = k_ws + (kbase + (c1 & 63)) * 48 + (c1 >> 6) * 8;
        step1 = 48;
    } else {
        c1 = t - 128;
        int vkhi = c1 / 48, dd = c1 - vkhi * 48;
        s1p = vt_ws + (vbase + dd) * SEQ + vkhi * 8;
        step1 = 1;
    }
    // chunk2: V chunk t+128 (all waves V)
    const int c2 = t + 128;
    const int vkhi2 = c2 / 48, dd2 = c2 - vkhi2 * 48;
    const unsigned short* s2p = vt_ws + (vbase + dd2) * SEQ + vkhi2 * 8;

    // ---- Q fragments (3 k-slices of 16), pre-scaled by SCALE*log2e ----
    bf16x8 qf[3];
    {
        const unsigned short* qp = q_ws + (kbase + q0 + q31) * DHEAD + hi * 8;
        #pragma unroll
        for (int ks = 0; ks < 3; ++ks)
            qf[ks] = *reinterpret_cast<const bf16x8*>(qp + ks * 16);
    }

    const int vrow1m = (32 + q31 > 47) ? 47 : (32 + q31);  // dup row 47, outputs discarded

    floatx16 oa0 = ZERO16, oa1 = ZERO16;
    float m_prev = -INFINITY, l_sum = 0.f;

    // ---- prologue: stage tile 0 into buffer 0 ----
    gload16(s0p, &k_lds[0][t * 8]);
    gload16(s1p, c1k ? &k_lds[0][c1 * 8] : &v_lds[0][c1 * 8]);
    gload16(s2p, &v_lds[0][c2 * 8]);
    __syncthreads();

    #pragma unroll 1
    for (int kt = 0; kt < 16; ++kt) {
        const int cur = kt & 1;
        // ---- issue next tile's async loads (land under this tile's compute) ----
        if (kt < 15) {
            const size_t kt0n = (size_t)(kt + 1) * 64;
            gload16(s0p + kt0n * 48,   &k_lds[cur ^ 1][t * 8]);
            gload16(s1p + kt0n * step1, c1k ? &k_lds[cur ^ 1][c1 * 8] : &v_lds[cur ^ 1][c1 * 8]);
            gload16(s2p + kt0n,        &v_lds[cur ^ 1][c2 * 8]);
        }

        const unsigned short* kb = k_lds[cur];
        const unsigned short* vb = v_lds[cur];

        // ---- fragments from LDS (stride-16, conflict-free) ----
        bf16x8 kf[6], vf0[4], vf1[4];
        #pragma unroll
        for (int ks = 0; ks < 3; ++ks) {
            kf[ks]     = *reinterpret_cast<const bf16x8*>(&kb[((ks * 2 + hi) * 64 + q31) * 8]);
            kf[ks + 3] = *reinterpret_cast<const bf16x8*>(&kb[((ks * 2 + hi) * 64 + q31 + 32) * 8]);
        }
        #pragma unroll
        for (int ksv = 0; ksv < 4; ++ksv) {
            vf0[ksv] = *reinterpret_cast<const bf16x8*>(&vb[((ksv * 2 + hi) * 48 + q31) * 8]);
            vf1[ksv] = *reinterpret_cast<const bf16x8*>(&vb[((ksv * 2 + hi) * 48 + vrow1m) * 8]);
        }

        // ---- S^T = K . Q^T ----
        floatx16 s0 = ZERO16, s1 = ZERO16;
        __builtin_amdgcn_s_setprio(1);
        #pragma unroll
        for (int ks = 0; ks < 3; ++ks) {
            s0 = __builtin_amdgcn_mfma_f32_32x32x16_bf16(kf[ks],     qf[ks], s0, 0, 0, 0);
            s1 = __builtin_amdgcn_mfma_f32_32x32x16_bf16(kf[ks + 3], qf[ks], s1, 0, 0, 0);
        }
        __builtin_amdgcn_s_setprio(0);

        // ---- online softmax (R3 proven form) ----
        float tmax = fmaxf(s0[0], s1[0]);
        #pragma unroll
        for (int r = 1; r < 16; ++r) tmax = fmaxf(tmax, fmaxf(s0[r], s1[r]));
        tmax = fmaxf(tmax, __shfl_xor(tmax, 32, 64));

        if (!__all((int)(tmax <= m_prev + RESCALE_THR))) {
            const float mnew = fmaxf(m_prev, tmax);
            const float scale = exp2f(m_prev - mnew);
            m_prev = mnew;
            l_sum *= scale;
            oa0 = oa0 * scale;
            oa1 = oa1 * scale;
        }
        const float mref = m_prev;

        float ts = 0.f;
        union U { bf16x8 v; unsigned wd[4]; };
        __builtin_amdgcn_s_setprio(1);
        #pragma unroll
        for (int kvb = 0; kvb < 2; ++kvb) {
            unsigned W[8], X[8];
            #pragma unroll
            for (int u = 0; u < 8; ++u) {
                float e0 = __builtin_amdgcn_exp2f((kvb ? s1[2*u]   : s0[2*u])   - mref);
                float e1 = __builtin_amdgcn_exp2f((kvb ? s1[2*u+1] : s0[2*u+1]) - mref);
                ts += e0 + e1;
                W[u] = pk2(e0, e1);
                X[u] = __shfl_xor(W[u], 32, 64);
            }
            #pragma unroll
            for (int s = 0; s < 2; ++s) {
                const int a = s * 4;
                U pf;
                pf.wd[0] = hi ? X[a+2] : W[a];
                pf.wd[1] = hi ? X[a+3] : W[a+1];
                pf.wd[2] = hi ? W[a+2] : X[a];
                pf.wd[3] = hi ? W[a+3] : X[a+1];
                const int ksv = kvb * 2 + s;
                oa0 = __builtin_amdgcn_mfma_f32_32x32x16_bf16(vf0[ksv], pf.v, oa0, 0, 0, 0);
                oa1 = __builtin_amdgcn_mfma_f32_32x32x16_bf16(vf1[ksv], pf.v, oa1, 0, 0, 0);
            }
        }
        __builtin_amdgcn_s_setprio(0);
        ts += __shfl_xor(ts, 32, 64);
        l_sum += ts;

        // one barrier per tile: drains gload_lds (vmcnt) + guards buffer reuse
        __syncthreads();
    }

    // ---- normalize + write z [bp][n][192] bf16 (paired u32 stores) ----
    const float inv = 1.0f / l_sum;
    unsigned* zp = reinterpret_cast<unsigned*>(
        z_ws + ((size_t)bp * SEQ + q0 + q31) * DMODEL + h * DHEAD);
    #pragma unroll
    for (int u = 0; u < 8; ++u) {
        int dd = 2 * (u & 1) + 8 * (u >> 1) + 4 * hi;       // d, d+1
        zp[dd >> 1] = pk2(oa0[2*u] * inv, oa0[2*u+1] * inv);
    }
    #pragma unroll
    for (int u = 0; u < 4; ++u) {
        int dd = 32 + 2 * (u & 1) + 8 * (u >> 1) + 4 * hi;  // 32..47 only
        zp[dd >> 1] = pk2(oa1[2*u] * inv, oa1[2*u+1] * inv);
    }
}

// ---------------------------------------------------------------------------
// Kernel 3: output projection (unchanged — proven).
// ---------------------------------------------------------------------------
__global__ __launch_bounds__(256) void proj_kernel(
    const unsigned short* __restrict__ z_ws,
    const float* __restrict__ w_proj,
    const float* __restrict__ b_proj,
    float* __restrict__ out)
{
    __shared__ unsigned short a_lds[64 * 200];
    __shared__ unsigned short w_lds[64 * 200];
    const int t = threadIdx.x;
    const int m0 = blockIdx.x * 64;
    const int n0 = blockIdx.y * 64;

    for (int i = t; i < 1536; i += 256) {
        int row = i / 24, c8 = i % 24;
        *reinterpret_cast<bf16x8*>(&a_lds[row * 200 + c8 * 8]) =
            *reinterpret_cast<const bf16x8*>(&z_ws[(size_t)(m0 + row) * DMODEL + c8 * 8]);
    }
    #pragma unroll
    for (int i = 0; i < 12; ++i) {
        int idx = t + i * 256;
        int row = idx / 48, c4 = idx % 48;
        float4 v = *reinterpret_cast<const float4*>(w_proj + (size_t)(n0 + row) * DMODEL + c4 * 4);
        uintx2 p; p.x = pk2(v.x, v.y); p.y = pk2(v.z, v.w);
        *reinterpret_cast<uintx2*>(&w_lds[row * 200 + c4 * 4]) = p;
    }
    __syncthreads();

    const int lane = t & 63, w = t >> 6;
    const int lrow = lane & 15, lhi = lane >> 4;

    floatx4 zf = {0.f, 0.f, 0.f, 0.f};
    floatx4 acc[4] = {zf, zf, zf, zf};

    #pragma unroll
    for (int ks = 0; ks < 6; ++ks) {
        bf16x8 af = *reinterpret_cast<const bf16x8*>(&a_lds[(w * 16 + lrow) * 200 + ks * 32 + lhi * 8]);
        #pragma unroll
        for (int cb = 0; cb < 4; ++cb) {
            bf16x8 bfr = *reinterpret_cast<const bf16x8*>(&w_lds[(cb * 16 + lrow) * 200 + ks * 32 + lhi * 8]);
            acc[cb] = __builtin_amdgcn_mfma_f32_16x16x32_bf16(af, bfr, acc[cb], 0, 0, 0);
        }
    }

    #pragma unroll
    for (int cb = 0; cb < 4; ++cb) {
        int c = n0 + cb * 16 + lrow;
        float bias = b_proj[c];
        #pragma unroll
        for (int r = 0; r < 4; ++r) {
            int m = m0 + w * 16 + lhi * 4 + r;
            out[(size_t)m * DMODEL + c] = acc[cb][r] + bias;
        }
    }
}

// ---------------------------------------------------------------------------
extern "C" void kernel_launch(void* const* d_in, const int* in_sizes, int n_in,
                              void* d_out, int out_size, void* d_ws, size_t ws_size,
                              hipStream_t stream) {
    const float* x      = (const float*)d_in[0];
    const float* w_qkv  = (const float*)d_in[1];
    const float* b_qkv  = (const float*)d_in[2];
    const float* w_proj = (const float*)d_in[3];
    const float* b_proj = (const float*)d_in[4];
    float* out = (float*)d_out;

    unsigned short* q_ws  = (unsigned short*)d_ws;
    unsigned short* k_ws  = q_ws  + (size_t)BPH * SEQ * DHEAD;   // 6.29M elems each
    unsigned short* vt_ws = k_ws  + (size_t)BPH * SEQ * DHEAD;
    unsigned short* z_ws  = vt_ws + (size_t)BPH * DHEAD * SEQ;
    // total ws usage: 4 * 12.58 MB = 50.3 MB

    qkv_kernel<<<dim3(512, 9), 256, 0, stream>>>(x, w_qkv, b_qkv, q_ws, k_ws, vt_ws);
    attn_kernel<<<1024, 256, 0, stream>>>(q_ws, k_ws, vt_ws, z_ws);
    proj_kernel<<<dim3(512, 3), 256, 0, stream>>>(z_ws, w_proj, b_proj, out);
}

// Round 8
// 116.396 us; speedup vs baseline: 2.0328x; 1.0234x over previous
//
#include <hip/hip_runtime.h>
#include <hip/hip_bf16.h>
#include <cstdint>
#include <cstddef>

typedef __attribute__((ext_vector_type(8))) short bf16x8;
typedef __attribute__((ext_vector_type(4))) short bf16x4;
typedef __attribute__((ext_vector_type(4))) float floatx4;
typedef __attribute__((ext_vector_type(16))) float floatx16;
typedef __attribute__((ext_vector_type(2))) unsigned uintx2;

#define SCALE_L2E 0.20823560929138437f  /* (1/sqrt(48)) * log2(e) */

#define BPH 128          // B*P*H = 8*4*4
#define SEQ 1024
#define DMODEL 192
#define DHEAD 48
#define MROWS 32768      // B*P*N
#define RESCALE_THR 11.5f  /* log2 domain ~ e^8 */
#define VSTRIDE 49152    // elems per bph in v2_ws: 128 ngrp * 48 d * 8

#define ZERO16 {0.f,0.f,0.f,0.f,0.f,0.f,0.f,0.f,0.f,0.f,0.f,0.f,0.f,0.f,0.f,0.f}

__device__ __forceinline__ unsigned short bfu(float f) {
    return __bfloat16_as_ushort(__float2bfloat16(f));
}
__device__ __forceinline__ unsigned pk2(float lo, float hi) {
    return (unsigned)bfu(lo) | ((unsigned)bfu(hi) << 16);
}

// K=8 bf16 MFMA (A,B: 4 bf16 = 2 VGPR; C/D: 16 f32). Prefer the builtin.
#if __has_builtin(__builtin_amdgcn_mfma_f32_32x32x8bf16_1k)
__device__ __forceinline__ floatx16 mfma8(bf16x4 a, bf16x4 b, floatx16 c) {
    return __builtin_amdgcn_mfma_f32_32x32x8bf16_1k(a, b, c, 0, 0, 0);
}
#else
__device__ __forceinline__ floatx16 mfma8(bf16x4 a, bf16x4 b, floatx16 c) {
    asm("v_mfma_f32_32x32x8_bf16 %0, %1, %2, %0" : "+v"(c) : "v"(a), "v"(b));
    return c;
}
#endif

// ---------------------------------------------------------------------------
// Kernel 1: QKV projection. q (scaled) / k -> [bph][n][48] bf16.
// v -> v2_ws [bph][n>>3][48][8] bf16 (PV B-fragment layout), via LDS transpose.
// ---------------------------------------------------------------------------
__global__ __launch_bounds__(256) void qkv_kernel(
    const float* __restrict__ x,
    const float* __restrict__ w_qkv,
    const float* __restrict__ b_qkv,
    unsigned short* __restrict__ q_ws,
    unsigned short* __restrict__ k_ws,
    unsigned short* __restrict__ v2_ws)
{
    __shared__ unsigned short a_lds[64 * 200];
    __shared__ unsigned short w_lds[64 * 200];
    const int t = threadIdx.x;
    const int m0 = blockIdx.x * 64;
    const int n0 = blockIdx.y * 64;

    #pragma unroll
    for (int i = 0; i < 12; ++i) {
        int idx = t + i * 256;
        int row = idx / 48, c4 = idx % 48;
        float4 v = *reinterpret_cast<const float4*>(x + (size_t)(m0 + row) * DMODEL + c4 * 4);
        uintx2 p; p.x = pk2(v.x, v.y); p.y = pk2(v.z, v.w);
        *reinterpret_cast<uintx2*>(&a_lds[row * 200 + c4 * 4]) = p;
    }
    #pragma unroll
    for (int i = 0; i < 12; ++i) {
        int idx = t + i * 256;
        int row = idx / 48, c4 = idx % 48;
        float4 v = *reinterpret_cast<const float4*>(w_qkv + (size_t)(n0 + row) * DMODEL + c4 * 4);
        uintx2 p; p.x = pk2(v.x, v.y); p.y = pk2(v.z, v.w);
        *reinterpret_cast<uintx2*>(&w_lds[row * 200 + c4 * 4]) = p;
    }
    __syncthreads();

    const int lane = t & 63, w = t >> 6;
    const int lrow = lane & 15, lhi = lane >> 4;

    floatx4 zf = {0.f, 0.f, 0.f, 0.f};
    floatx4 acc[4] = {zf, zf, zf, zf};

    #pragma unroll
    for (int ks = 0; ks < 6; ++ks) {
        bf16x8 af = *reinterpret_cast<const bf16x8*>(&a_lds[(w * 16 + lrow) * 200 + ks * 32 + lhi * 8]);
        #pragma unroll
        for (int cb = 0; cb < 4; ++cb) {
            bf16x8 bfr = *reinterpret_cast<const bf16x8*>(&w_lds[(cb * 16 + lrow) * 200 + ks * 32 + lhi * 8]);
            acc[cb] = __builtin_amdgcn_mfma_f32_16x16x32_bf16(af, bfr, acc[cb], 0, 0, 0);
        }
    }

    const int sec = n0 / 192;  // 0=q, 1=k, 2=v (uniform per block)
    if (sec == 2) {
        // V: transpose through LDS -> [ngrp][d][8] stores
        __syncthreads();  // a_lds reads done; reuse as [64 c][72 pad] tile
        #pragma unroll
        for (int cb = 0; cb < 4; ++cb) {
            float bias = b_qkv[n0 + cb * 16 + lrow];
            #pragma unroll
            for (int r = 0; r < 4; ++r)
                a_lds[(cb * 16 + lrow) * 72 + (w * 16 + lhi * 4 + r)] = bfu(acc[cb][r] + bias);
        }
        __syncthreads();
        const int bp = m0 >> 10, nb = m0 & 1023;
        #pragma unroll
        for (int i = 0; i < 2; ++i) {
            int ch = t + i * 256;
            int c_local = ch >> 3, seg = ch & 7;      // c_local: 0..191 local col, seg: n-subgroup
            int cc = n0 + c_local - 384;              // 0..191
            int h = cc / 48, dd = cc - h * 48;
            *reinterpret_cast<bf16x8*>(
                &v2_ws[(size_t)(bp * 4 + h) * VSTRIDE + (size_t)(nb / 8 + seg) * 384 + dd * 8]) =
                *reinterpret_cast<const bf16x8*>(&a_lds[c_local * 72 + seg * 8]);
        }
    } else {
        #pragma unroll
        for (int cb = 0; cb < 4; ++cb) {
            int c = n0 + cb * 16 + lrow;
            int cc = c - sec * 192;
            int h = cc / 48, dd = cc - h * 48;
            float bias = b_qkv[c];
            #pragma unroll
            for (int r = 0; r < 4; ++r) {
                int m = m0 + w * 16 + lhi * 4 + r;
                float val = acc[cb][r] + bias;
                int bp = m >> 10, n = m & 1023;
                int bph = bp * 4 + h;
                if (sec == 0) {
                    q_ws[((size_t)bph * SEQ + n) * DHEAD + dd] = bfu(val * SCALE_L2E);
                } else {
                    k_ws[((size_t)bph * SEQ + n) * DHEAD + dd] = bfu(val);
                }
            }
        }
    }
}

// ---------------------------------------------------------------------------
// Kernel 2: flash attention, R3 structure (no LDS, no barriers, direct L2
// loads, XCD swizzle) + zero-shuffle PV: O = mfma8(P_local, V_frag) using
// K=8 MFMAs whose A-layout (lane supplies k=4*hi..+3) exactly matches the
// S^T register ownership (kv = 8j+4hi+s). P never leaves the lane.
// C layout of O: col = d (lane&31), row = q via (r&3)+8(r>>2)+4hi.
// ---------------------------------------------------------------------------
__global__ __launch_bounds__(256, 4) void attn_kernel(
    const unsigned short* __restrict__ q_ws,
    const unsigned short* __restrict__ k_ws,
    const unsigned short* __restrict__ v2_ws,
    unsigned short* __restrict__ z_ws)
{
    const int t = threadIdx.x, lane = t & 63, w = t >> 6;
    const int q31 = lane & 31, hi = lane >> 5;
    const int d = blockIdx.x;
    const int bph = (d & 7) | ((d >> 6) << 3);
    const int qc = (d >> 3) & 7;
    const int q0 = qc * 128 + w * 32;
    const int bp = bph >> 2, h = bph & 3;

    // Q fragments (3 k-slices of 16), pre-scaled by SCALE*log2e
    bf16x8 qf[3];
    {
        const unsigned short* qp = q_ws + ((size_t)bph * SEQ + q0 + q31) * DHEAD + hi * 8;
        #pragma unroll
        for (int ks = 0; ks < 3; ++ks)
            qf[ks] = *reinterpret_cast<const bf16x8*>(qp + ks * 16);
    }

    const unsigned short* kp = k_ws + ((size_t)bph * SEQ + q31) * DHEAD + hi * 8;
    // V B-fragments: lane (col,hi) reads bf16x4 at [ngrp=8kt+j][d][4*hi]
    const int dB = 32 + (q31 < 16 ? q31 : 15);   // set1 col; lanes 16-31 dup d=47 (cols unused)
    const unsigned short* vpA = v2_ws + (size_t)bph * VSTRIDE + q31 * 8 + hi * 4;
    const unsigned short* vpB = v2_ws + (size_t)bph * VSTRIDE + dB  * 8 + hi * 4;

    floatx16 oa0 = ZERO16, oa1 = ZERO16;   // d-sets 0-31, 32-47
    float m_prev = -INFINITY, l_sum = 0.f;

    #pragma unroll 1
    for (int kt = 0; kt < 16; ++kt) {
        // ---- all tile loads up front (latency under QK^T + softmax) ----
        const unsigned short* kpt = kp + (size_t)kt * 64 * DHEAD;
        bf16x8 kf[6];
        #pragma unroll
        for (int ks = 0; ks < 3; ++ks) {
            kf[ks]     = *reinterpret_cast<const bf16x8*>(kpt + ks * 16);
            kf[ks + 3] = *reinterpret_cast<const bf16x8*>(kpt + 32 * DHEAD + ks * 16);
        }
        bf16x4 vA[8], vB[8];
        const size_t vto = (size_t)kt * 3072;
        #pragma unroll
        for (int j = 0; j < 8; ++j) {
            vA[j] = *reinterpret_cast<const bf16x4*>(vpA + vto + j * 384);
            vB[j] = *reinterpret_cast<const bf16x4*>(vpB + vto + j * 384);
        }

        // ---- S^T = K . Q^T ----
        floatx16 s0 = ZERO16, s1 = ZERO16;
        __builtin_amdgcn_s_setprio(1);
        #pragma unroll
        for (int ks = 0; ks < 3; ++ks) {
            s0 = __builtin_amdgcn_mfma_f32_32x32x16_bf16(kf[ks],     qf[ks], s0, 0, 0, 0);
            s1 = __builtin_amdgcn_mfma_f32_32x32x16_bf16(kf[ks + 3], qf[ks], s1, 0, 0, 0);
        }
        __builtin_amdgcn_s_setprio(0);

        // ---- online softmax (per-lane, q = q31) ----
        float tmax = fmaxf(s0[0], s1[0]);
        #pragma unroll
        for (int r = 1; r < 16; ++r) tmax = fmaxf(tmax, fmaxf(s0[r], s1[r]));
        tmax = fmaxf(tmax, __shfl_xor(tmax, 32, 64));

        if (!__all((int)(tmax <= m_prev + RESCALE_THR))) {
            const float mnew = fmaxf(m_prev, tmax);
            const float scale = exp2f(m_prev - mnew);
            m_prev = mnew;
            l_sum *= scale;
            // O rows are q_r = (r&3)+8*(r>>2)+4*hi -> fetch that q's scale
            #pragma unroll
            for (int r = 0; r < 16; ++r) {
                float sr = __shfl(scale, (r & 3) + 8 * (r >> 2) + 4 * hi, 64);
                oa0[r] *= sr;
                oa1[r] *= sr;
            }
        }
        const float mref = m_prev;

        // ---- exp + pack + PV (fully lane-local A-operand) ----
        float ts = 0.f;
        union AU { bf16x4 v; unsigned u[2]; };
        __builtin_amdgcn_s_setprio(1);
        #pragma unroll
        for (int j = 0; j < 8; ++j) {
            float e0, e1, e2, e3;
            if (j < 4) {
                e0 = __builtin_amdgcn_exp2f(s0[4*j]   - mref);
                e1 = __builtin_amdgcn_exp2f(s0[4*j+1] - mref);
                e2 = __builtin_amdgcn_exp2f(s0[4*j+2] - mref);
                e3 = __builtin_amdgcn_exp2f(s0[4*j+3] - mref);
            } else {
                e0 = __builtin_amdgcn_exp2f(s1[4*(j-4)]   - mref);
                e1 = __builtin_amdgcn_exp2f(s1[4*(j-4)+1] - mref);
                e2 = __builtin_amdgcn_exp2f(s1[4*(j-4)+2] - mref);
                e3 = __builtin_amdgcn_exp2f(s1[4*(j-4)+3] - mref);
            }
            ts += (e0 + e1) + (e2 + e3);
            AU aj;
            aj.u[0] = pk2(e0, e1);
            aj.u[1] = pk2(e2, e3);
            oa0 = mfma8(aj.v, vA[j], oa0);
            oa1 = mfma8(aj.v, vB[j], oa1);
        }
        __builtin_amdgcn_s_setprio(0);
        ts += __shfl_xor(ts, 32, 64);
        l_sum += ts;
    }

    // ---- normalize + write z [bp][n][192] bf16 ----
    // O C-layout: col(d) = q31, row(q) = q0 + (r&3)+8*(r>>2)+4*hi.
    const float inv = 1.0f / l_sum;   // for q = q31 (replicated both halves)
    #pragma unroll
    for (int r = 0; r < 16; ++r) {
        const int qr = (r & 3) + 8 * (r >> 2) + 4 * hi;
        const float ir = __shfl(inv, qr, 64);
        unsigned short* zr = z_ws + ((size_t)bp * SEQ + q0 + qr) * DMODEL + h * DHEAD;
        zr[q31] = bfu(oa0[r] * ir);                     // d = q31 (0..31), 64B/wave coalesced
        if (q31 < 16) zr[32 + q31] = bfu(oa1[r] * ir);  // d = 32..47
    }
}

// ---------------------------------------------------------------------------
// Kernel 3: output projection (unchanged — proven).
// ---------------------------------------------------------------------------
__global__ __launch_bounds__(256) void proj_kernel(
    const unsigned short* __restrict__ z_ws,
    const float* __restrict__ w_proj,
    const float* __restrict__ b_proj,
    float* __restrict__ out)
{
    __shared__ unsigned short a_lds[64 * 200];
    __shared__ unsigned short w_lds[64 * 200];
    const int t = threadIdx.x;
    const int m0 = blockIdx.x * 64;
    const int n0 = blockIdx.y * 64;

    for (int i = t; i < 1536; i += 256) {
        int row = i / 24, c8 = i % 24;
        *reinterpret_cast<bf16x8*>(&a_lds[row * 200 + c8 * 8]) =
            *reinterpret_cast<const bf16x8*>(&z_ws[(size_t)(m0 + row) * DMODEL + c8 * 8]);
    }
    #pragma unroll
    for (int i = 0; i < 12; ++i) {
        int idx = t + i * 256;
        int row = idx / 48, c4 = idx % 48;
        float4 v = *reinterpret_cast<const float4*>(w_proj + (size_t)(n0 + row) * DMODEL + c4 * 4);
        uintx2 p; p.x = pk2(v.x, v.y); p.y = pk2(v.z, v.w);
        *reinterpret_cast<uintx2*>(&w_lds[row * 200 + c4 * 4]) = p;
    }
    __syncthreads();

    const int lane = t & 63, w = t >> 6;
    const int lrow = lane & 15, lhi = lane >> 4;

    floatx4 zf = {0.f, 0.f, 0.f, 0.f};
    floatx4 acc[4] = {zf, zf, zf, zf};

    #pragma unroll
    for (int ks = 0; ks < 6; ++ks) {
        bf16x8 af = *reinterpret_cast<const bf16x8*>(&a_lds[(w * 16 + lrow) * 200 + ks * 32 + lhi * 8]);
        #pragma unroll
        for (int cb = 0; cb < 4; ++cb) {
            bf16x8 bfr = *reinterpret_cast<const bf16x8*>(&w_lds[(cb * 16 + lrow) * 200 + ks * 32 + lhi * 8]);
            acc[cb] = __builtin_amdgcn_mfma_f32_16x16x32_bf16(af, bfr, acc[cb], 0, 0, 0);
        }
    }

    #pragma unroll
    for (int cb = 0; cb < 4; ++cb) {
        int c = n0 + cb * 16 + lrow;
        float bias = b_proj[c];
        #pragma unroll
        for (int r = 0; r < 4; ++r) {
            int m = m0 + w * 16 + lhi * 4 + r;
            out[(size_t)m * DMODEL + c] = acc[cb][r] + bias;
        }
    }
}

// ---------------------------------------------------------------------------
extern "C" void kernel_launch(void* const* d_in, const int* in_sizes, int n_in,
                              void* d_out, int out_size, void* d_ws, size_t ws_size,
                              hipStream_t stream) {
    const float* x      = (const float*)d_in[0];
    const float* w_qkv  = (const float*)d_in[1];
    const float* b_qkv  = (const float*)d_in[2];
    const float* w_proj = (const float*)d_in[3];
    const float* b_proj = (const float*)d_in[4];
    float* out = (float*)d_out;

    unsigned short* q_ws  = (unsigned short*)d_ws;
    unsigned short* k_ws  = q_ws  + (size_t)BPH * SEQ * DHEAD;   // 6.29M elems each
    unsigned short* v2_ws = k_ws  + (size_t)BPH * SEQ * DHEAD;
    unsigned short* z_ws  = v2_ws + (size_t)BPH * VSTRIDE;
    // total ws usage: 4 * 12.58 MB = 50.3 MB

    qkv_kernel<<<dim3(512, 9), 256, 0, stream>>>(x, w_qkv, b_qkv, q_ws, k_ws, v2_ws);
    attn_kernel<<<1024, 256, 0, stream>>>(q_ws, k_ws, v2_ws, z_ws);
    proj_kernel<<<dim3(512, 3), 256, 0, stream>>>(z_ws, w_proj, b_proj, out);
}